// Round 8
// baseline (93.491 us; speedup 1.0000x reference)
//
#include <hip/hip_runtime.h>

// GAT block, algebraically collapsed:
//   d[b,f,n]     = softmax_n( x[b,:,f,n] . (W @ a2) )[n] * mask[n,n]
//   out[b,h,f,n] = d[b,f,n] * (sum_c x[b,c,f,n]*W[c,h] + bW[h])
// (s1, ab, bW.a2 cancel inside the row-softmax — constant over the softmax axis.)
//
// R8: test WRITE LINEARITY. K1 (proven) computes d into ws. K2 writes each
// (b,h) plane as a strictly linear sweep: grid = 1024 blocks = XCD-pinned b
// x 32 h-pairs; block loops 50 steps, 2 NT stores/thread/step, ascending
// addresses. x[b]+d[b] (819 KB) stay resident in that XCD's L2.

typedef float vfloat4 __attribute__((ext_vector_type(4)));

namespace {
constexpr int B_ = 32, C_ = 3, F_ = 2048, N_ = 25, H_ = 64;
constexpr int FN   = F_ * N_;       // 51200 floats per plane
constexpr int FN4  = FN / 4;        // 12800 float4 per plane
constexpr int TF   = 64;            // frames per K1 tile
constexpr int TPOS = TF * N_;       // 1600
constexpr int TVEC = TPOS / 4;      // 400
constexpr int THREADS = 256;
constexpr int STEPS = FN4 / THREADS; // 50
constexpr size_t D_BYTES = (size_t)B_ * FN * sizeof(float);  // 6.55 MB
}

// ---------------- K1: diag-scale d[b, f*n] -> ws (proven R2 kernel) ----------------
__global__ __launch_bounds__(THREADS) void gat_diag(
    const float* __restrict__ x, const float* __restrict__ mask,
    const float* __restrict__ W, const float* __restrict__ a2,
    float* __restrict__ dout)
{
  __shared__ vfloat4 x4[3 * TVEC];
  __shared__ vfloat4 d4[TVEC];
  __shared__ float mdl[N_];
  __shared__ float wal[C_];

  const int tid = threadIdx.x;
  const int blk = blockIdx.x;
  const int b  = blk >> 5;
  const int ft = blk & 31;
  const size_t fbase = (size_t)ft * TPOS;

  if (tid < N_) mdl[tid] = mask[tid * N_ + tid];
  if (tid >= 64 && tid < 64 + C_) {
    const int c = tid - 64;
    float s = 0.f;
    for (int h = 0; h < H_; ++h) s += W[c * H_ + h] * a2[h];
    wal[c] = s;
  }

  const vfloat4* xg = (const vfloat4*)x;
  for (int i = tid; i < 3 * TVEC; i += THREADS) {
    int c = i / TVEC;
    int j = i - c * TVEC;
    x4[i] = xg[(size_t)(b * 3 + c) * FN4 + (fbase >> 2) + j];
  }
  __syncthreads();

  if (tid < TF) {
    const float* xl = (const float*)x4;
    const float wa0 = wal[0], wa1 = wal[1], wa2 = wal[2];
    const int base = tid * N_;
    float s[N_];
    float m = -3.0e38f;
#pragma unroll
    for (int n = 0; n < N_; ++n) {
      float v = fmaf(xl[2 * TPOS + base + n], wa2,
                fmaf(xl[TPOS + base + n], wa1, xl[base + n] * wa0));
      s[n] = v;
      m = fmaxf(m, v);
    }
    float z = 0.f;
#pragma unroll
    for (int n = 0; n < N_; ++n) { s[n] = __expf(s[n] - m); z += s[n]; }
    const float inv = 1.f / z;
    float* dl = (float*)d4;
#pragma unroll
    for (int n = 0; n < N_; ++n) dl[base + n] = s[n] * inv * mdl[n];
  }
  __syncthreads();

  vfloat4* dg = (vfloat4*)dout;
  const size_t db = ((size_t)b * FN + fbase) >> 2;
  dg[db + tid] = d4[tid];
  if (tid < TVEC - THREADS) dg[db + THREADS + tid] = d4[THREADS + tid];
}

// ---------------- K2: plane-linear streaming writer ----------------
__global__ __launch_bounds__(THREADS) void gat_write2(
    const float* __restrict__ x, const float* __restrict__ d,
    const float* __restrict__ W, const float* __restrict__ bW,
    float* __restrict__ out)
{
  const int tid = threadIdx.x;
  const int blk = blockIdx.x;          // 1024 = 8 xcd * 4 b * 32 hpairs
  const int xcd = blk & 7;             // HW round-robins consecutive blk across XCDs
  const int idx = blk >> 3;            // 0..127 within this XCD
  const int b   = xcd * 4 + (idx >> 5);
  const int hp  = idx & 31;
  const int h0  = hp * 2, h1 = h0 + 1;

  // per-block uniform weights -> SGPRs
  const float w00 = W[h0], w01 = W[H_ + h0], w02 = W[2 * H_ + h0], bw0 = bW[h0];
  const float w10 = W[h1], w11 = W[H_ + h1], w12 = W[2 * H_ + h1], bw1 = bW[h1];

  const vfloat4* xg = (const vfloat4*)x;
  const vfloat4* dg = (const vfloat4*)d;
  vfloat4* og = (vfloat4*)out;

  const size_t xb0 = (size_t)(b * 3 + 0) * FN4;
  const size_t xb1 = (size_t)(b * 3 + 1) * FN4;
  const size_t xb2 = (size_t)(b * 3 + 2) * FN4;
  const size_t db  = (size_t)b * FN4;
  const size_t ob0 = (size_t)(b * H_ + h0) * FN4;
  const size_t ob1 = (size_t)(b * H_ + h1) * FN4;

#pragma unroll 2
  for (int s = 0; s < STEPS; ++s) {
    const int j = s * THREADS + tid;
    const vfloat4 x0 = xg[xb0 + j];
    const vfloat4 x1 = xg[xb1 + j];
    const vfloat4 x2 = xg[xb2 + j];
    const vfloat4 dd = dg[db + j];
    vfloat4 t;
    t.x = fmaf(x2.x, w02, fmaf(x1.x, w01, fmaf(x0.x, w00, bw0)));
    t.y = fmaf(x2.y, w02, fmaf(x1.y, w01, fmaf(x0.y, w00, bw0)));
    t.z = fmaf(x2.z, w02, fmaf(x1.z, w01, fmaf(x0.z, w00, bw0)));
    t.w = fmaf(x2.w, w02, fmaf(x1.w, w01, fmaf(x0.w, w00, bw0)));
    vfloat4 o0 = {dd.x * t.x, dd.y * t.y, dd.z * t.z, dd.w * t.w};
    __builtin_nontemporal_store(o0, &og[ob0 + j]);
    t.x = fmaf(x2.x, w12, fmaf(x1.x, w11, fmaf(x0.x, w10, bw1)));
    t.y = fmaf(x2.y, w12, fmaf(x1.y, w11, fmaf(x0.y, w10, bw1)));
    t.z = fmaf(x2.z, w12, fmaf(x1.z, w11, fmaf(x0.z, w10, bw1)));
    t.w = fmaf(x2.w, w12, fmaf(x1.w, w11, fmaf(x0.w, w10, bw1)));
    vfloat4 o1 = {dd.x * t.x, dd.y * t.y, dd.z * t.z, dd.w * t.w};
    __builtin_nontemporal_store(o1, &og[ob1 + j]);
  }
}

// ---------------- fallback: R4 fused (best single-kernel, 81.4us) ----------------
namespace {
constexpr int JB   = FN4 / THREADS;  // 50
constexpr int MAXW = 264;
}

__global__ __launch_bounds__(THREADS) void gat_fused2(
    const float* __restrict__ x, const float* __restrict__ mask,
    const float* __restrict__ W, const float* __restrict__ bW,
    const float* __restrict__ a2, float* __restrict__ out)
{
  __shared__ float   xl[3][4 * MAXW];
  __shared__ float   dl[4 * MAXW];
  __shared__ vfloat4 Wp[H_];
  __shared__ float   mdl[N_];
  __shared__ float   wal[C_];

  const int tid = threadIdx.x;
  const int blk = blockIdx.x;
  const int b   = blk / JB;
  const int jb  = blk - b * JB;
  const int S   = jb * THREADS;
  const int p0  = S * 4;
  const int f0  = p0 / N_;
  const int f1  = (p0 + 4 * THREADS - 1) / N_;
  const int nf  = f1 - f0 + 1;
  const int A0  = (f0 * N_) & ~3;
  int A1 = (f1 * N_ + N_ + 3) & ~3;
  if (A1 > FN) A1 = FN;
  const int cnt4 = (A1 - A0) >> 2;

  const vfloat4* xg = (const vfloat4*)x;
#pragma unroll
  for (int c = 0; c < 3; ++c) {
    const vfloat4* src = xg + (size_t)(b * 3 + c) * FN4 + (A0 >> 2);
    vfloat4* dst = (vfloat4*)xl[c];
    for (int i = tid; i < cnt4; i += THREADS) dst[i] = src[i];
  }
  if (tid < H_) {
    vfloat4 w = {W[tid], W[H_ + tid], W[2 * H_ + tid], bW[tid]};
    Wp[tid] = w;
  } else if (tid < H_ + C_) {
    const int c = tid - H_;
    float s = 0.f;
    for (int h = 0; h < H_; ++h) s += W[c * H_ + h] * a2[h];
    wal[c] = s;
  }
  if (tid >= 128 && tid < 128 + N_) mdl[tid - 128] = mask[(tid - 128) * (N_ + 1)];
  __syncthreads();

  if (tid < nf) {
    const float wa0 = wal[0], wa1 = wal[1], wa2 = wal[2];
    const int base = (f0 + tid) * N_ - A0;
    float s[N_];
    float m = -3.0e38f;
#pragma unroll
    for (int n = 0; n < N_; ++n) {
      float v = fmaf(xl[2][base + n], wa2,
                fmaf(xl[1][base + n], wa1, xl[0][base + n] * wa0));
      s[n] = v;
      m = fmaxf(m, v);
    }
    float z = 0.f;
#pragma unroll
    for (int n = 0; n < N_; ++n) { s[n] = __expf(s[n] - m); z += s[n]; }
    const float inv = 1.f / z;
#pragma unroll
    for (int n = 0; n < N_; ++n) dl[base + n] = s[n] * inv * mdl[n];
  }
  __syncthreads();

  const int li = tid + S - (A0 >> 2);
  const vfloat4 x0 = ((const vfloat4*)xl[0])[li];
  const vfloat4 x1 = ((const vfloat4*)xl[1])[li];
  const vfloat4 x2 = ((const vfloat4*)xl[2])[li];
  const vfloat4 dd = ((const vfloat4*)dl)[li];

  vfloat4* og = (vfloat4*)out;
  const size_t ob = (size_t)b * H_ * FN4 + S + tid;
#pragma unroll 4
  for (int h = 0; h < H_; ++h) {
    const vfloat4 wv = Wp[h];
    vfloat4 o;
    o.x = dd.x * fmaf(x2.x, wv.z, fmaf(x1.x, wv.y, fmaf(x0.x, wv.x, wv.w)));
    o.y = dd.y * fmaf(x2.y, wv.z, fmaf(x1.y, wv.y, fmaf(x0.y, wv.x, wv.w)));
    o.z = dd.z * fmaf(x2.z, wv.z, fmaf(x1.z, wv.y, fmaf(x0.z, wv.x, wv.w)));
    o.w = dd.w * fmaf(x2.w, wv.z, fmaf(x1.w, wv.y, fmaf(x0.w, wv.x, wv.w)));
    __builtin_nontemporal_store(o, &og[ob + (size_t)h * FN4]);
  }
}

extern "C" void kernel_launch(void* const* d_in, const int* in_sizes, int n_in,
                              void* d_out, int out_size, void* d_ws, size_t ws_size,
                              hipStream_t stream) {
  const float* x    = (const float*)d_in[0];  // [B,C,F,N]
  const float* mask = (const float*)d_in[1];  // [N,N]
  const float* W    = (const float*)d_in[2];  // [C,H]
  const float* bW   = (const float*)d_in[3];  // [H]
  // d_in[4] = a1 (cancels), d_in[6] = ab (cancels)
  const float* a2   = (const float*)d_in[5];  // [H]
  float* out = (float*)d_out;                 // [B,H,F,N]

  if (ws_size >= D_BYTES && d_ws != nullptr) {
    float* d = (float*)d_ws;
    hipLaunchKernelGGL(gat_diag, dim3(B_ * (F_ / TF)), dim3(THREADS), 0, stream,
                       x, mask, W, a2, d);
    hipLaunchKernelGGL(gat_write2, dim3(B_ * (H_ / 2)), dim3(THREADS), 0, stream,
                       x, d, W, bW, out);
  } else {
    hipLaunchKernelGGL(gat_fused2, dim3(B_ * JB), dim3(THREADS), 0, stream,
                       x, mask, W, bW, a2, out);
  }
}

// Round 9
// 85.419 us; speedup vs baseline: 1.0945x; 1.0945x over previous
//
#include <hip/hip_runtime.h>

// GAT block, algebraically collapsed:
//   d[b,f,n]     = softmax_n( x[b,:,f,n] . (W @ a2) )[n] * mask[n,n]
//   out[b,h,f,n] = d[b,f,n] * (sum_c x[b,c,f,n]*W[c,h] + bW[h])
// (s1, ab, bW.a2 cancel inside the row-softmax — constant over the softmax axis.)
//
// R9 = R4 structure (best, 81.4us: fused, 1-slot/thread, NT stores, unroll 4)
// + software pipeline: 800 blocks x 2 windows. Window 2's x is prefetched into
// registers BEFORE window 1's 64-store loop, so its HBM latency hides under
// ~37us of stores; only the short softmax remains serial between windows.

typedef float vfloat4 __attribute__((ext_vector_type(4)));

namespace {
constexpr int B_ = 32, C_ = 3, F_ = 2048, N_ = 25, H_ = 64;
constexpr int FN   = F_ * N_;        // 51200 floats per plane
constexpr int FN4  = FN / 4;         // 12800 float4 per plane
constexpr int THREADS = 256;
constexpr int JB   = FN4 / THREADS;  // 50 windows per batch
constexpr int NW   = B_ * JB;        // 1600 windows
constexpr int BLOCKS = NW / 2;       // 800 blocks, 2 windows each
constexpr int MAXW = 264;            // max float4 per channel window
}

struct Geom { int b, S, nf, A0, cnt4; };

__device__ __forceinline__ Geom mk_geom(int w) {
  Geom g;
  g.b = w / JB;
  const int jb = w - g.b * JB;
  g.S = jb * THREADS;
  const int p0 = g.S * 4;
  const int f0 = p0 / N_;
  const int f1 = (p0 + 4 * THREADS - 1) / N_;
  g.nf = f1 - f0 + 1;                 // <= 42
  g.A0 = (f0 * N_) & ~3;
  int A1 = (f1 * N_ + N_ + 3) & ~3;
  if (A1 > FN) A1 = FN;
  g.cnt4 = (A1 - g.A0) >> 2;          // 257..264
  return g;
}

__global__ __launch_bounds__(THREADS) void gat_pipe(
    const float* __restrict__ x, const float* __restrict__ mask,
    const float* __restrict__ W, const float* __restrict__ bW,
    const float* __restrict__ a2, float* __restrict__ out)
{
  __shared__ float   xl[3][4 * MAXW];   // x window, per channel
  __shared__ float   dl[4 * MAXW];      // diag-scale per position
  __shared__ vfloat4 Wp[H_];            // {W0[h], W1[h], W2[h], bW[h]}
  __shared__ float   mdl[N_];
  __shared__ float   wal[C_];

  const int tid = threadIdx.x;
  const vfloat4* xg = (const vfloat4*)x;
  vfloat4* og = (vfloat4*)out;

  // ---- one-time params ----
  if (tid < H_) {
    vfloat4 w = {W[tid], W[H_ + tid], W[2 * H_ + tid], bW[tid]};
    Wp[tid] = w;
  } else if (tid < H_ + C_) {
    const int c = tid - H_;
    float s = 0.f;
    for (int h = 0; h < H_; ++h) s += W[c * H_ + h] * a2[h];
    wal[c] = s;
  }
  if (tid >= 128 && tid < 128 + N_) mdl[tid - 128] = mask[(tid - 128) * (N_ + 1)];

  // ---- window 1: stage ----
  const Geom g1 = mk_geom(blockIdx.x);
#pragma unroll
  for (int c = 0; c < 3; ++c) {
    const vfloat4* src = xg + (size_t)(g1.b * 3 + c) * FN4 + (g1.A0 >> 2);
    vfloat4* dst = (vfloat4*)xl[c];
    for (int i = tid; i < g1.cnt4; i += THREADS) dst[i] = src[i];
  }
  __syncthreads();

  // ---- window 1: softmax ----
  {
    const int f0 = g1.A0 / N_ + ((g1.A0 % N_) ? 1 : 0); // first full frame >= A0
    // NOTE: g1.A0 = (f0*N_)&~3 <= f0*N_; frames f0..f0+nf-1 relative base:
  }
  if (tid < g1.nf) {
    const float wa0 = wal[0], wa1 = wal[1], wa2 = wal[2];
    const int f0 = (g1.S * 4) / N_;
    const int base = (f0 + tid) * N_ - g1.A0;
    float s[N_];
    float m = -3.0e38f;
#pragma unroll
    for (int n = 0; n < N_; ++n) {
      float v = fmaf(xl[2][base + n], wa2,
                fmaf(xl[1][base + n], wa1, xl[0][base + n] * wa0));
      s[n] = v;
      m = fmaxf(m, v);
    }
    float z = 0.f;
#pragma unroll
    for (int n = 0; n < N_; ++n) { s[n] = __expf(s[n] - m); z += s[n]; }
    const float inv = 1.f / z;
#pragma unroll
    for (int n = 0; n < N_; ++n) dl[base + n] = s[n] * inv * mdl[n];
  }
  __syncthreads();

  // ---- window 1: pull regs ----
  const int li1 = tid + g1.S - (g1.A0 >> 2);
  const vfloat4 x0 = ((const vfloat4*)xl[0])[li1];
  const vfloat4 x1 = ((const vfloat4*)xl[1])[li1];
  const vfloat4 x2 = ((const vfloat4*)xl[2])[li1];
  const vfloat4 dd = ((const vfloat4*)dl)[li1];

  // ---- window 2: prefetch into registers (hidden under w1 stores) ----
  const Geom g2 = mk_geom(blockIdx.x + BLOCKS);
  const bool hv1 = (tid + THREADS) < g2.cnt4;   // slot tid always valid (cnt4>=257)
  vfloat4 pf0a, pf1a, pf2a, pf0b = {}, pf1b = {}, pf2b = {};
  {
    const vfloat4* s0 = xg + (size_t)(g2.b * 3 + 0) * FN4 + (g2.A0 >> 2);
    const vfloat4* s1 = xg + (size_t)(g2.b * 3 + 1) * FN4 + (g2.A0 >> 2);
    const vfloat4* s2 = xg + (size_t)(g2.b * 3 + 2) * FN4 + (g2.A0 >> 2);
    pf0a = s0[tid]; pf1a = s1[tid]; pf2a = s2[tid];
    if (hv1) { pf0b = s0[tid + THREADS]; pf1b = s1[tid + THREADS]; pf2b = s2[tid + THREADS]; }
  }

  // ---- window 1: store loop ----
  {
    const size_t ob = (size_t)g1.b * H_ * FN4 + g1.S + tid;
#pragma unroll 4
    for (int h = 0; h < H_; ++h) {
      const vfloat4 wv = Wp[h];
      vfloat4 o;
      o.x = dd.x * fmaf(x2.x, wv.z, fmaf(x1.x, wv.y, fmaf(x0.x, wv.x, wv.w)));
      o.y = dd.y * fmaf(x2.y, wv.z, fmaf(x1.y, wv.y, fmaf(x0.y, wv.x, wv.w)));
      o.z = dd.z * fmaf(x2.z, wv.z, fmaf(x1.z, wv.y, fmaf(x0.z, wv.x, wv.w)));
      o.w = dd.w * fmaf(x2.w, wv.z, fmaf(x1.w, wv.y, fmaf(x0.w, wv.x, wv.w)));
      __builtin_nontemporal_store(o, &og[ob + (size_t)h * FN4]);
    }
  }

  // ---- window 2: LDS fill from prefetch regs (no barrier needed before:
  //      nothing reads xl/dl during the store loop; all threads pulled their
  //      regs before it) ----
  {
    vfloat4* d0 = (vfloat4*)xl[0];
    vfloat4* d1 = (vfloat4*)xl[1];
    vfloat4* d2 = (vfloat4*)xl[2];
    d0[tid] = pf0a; d1[tid] = pf1a; d2[tid] = pf2a;
    if (hv1) { d0[tid + THREADS] = pf0b; d1[tid + THREADS] = pf1b; d2[tid + THREADS] = pf2b; }
  }
  __syncthreads();

  // ---- window 2: softmax ----
  if (tid < g2.nf) {
    const float wa0 = wal[0], wa1 = wal[1], wa2 = wal[2];
    const int f0 = (g2.S * 4) / N_;
    const int base = (f0 + tid) * N_ - g2.A0;
    float s[N_];
    float m = -3.0e38f;
#pragma unroll
    for (int n = 0; n < N_; ++n) {
      float v = fmaf(xl[2][base + n], wa2,
                fmaf(xl[1][base + n], wa1, xl[0][base + n] * wa0));
      s[n] = v;
      m = fmaxf(m, v);
    }
    float z = 0.f;
#pragma unroll
    for (int n = 0; n < N_; ++n) { s[n] = __expf(s[n] - m); z += s[n]; }
    const float inv = 1.f / z;
#pragma unroll
    for (int n = 0; n < N_; ++n) dl[base + n] = s[n] * inv * mdl[n];
  }
  __syncthreads();

  // ---- window 2: pull regs + store loop ----
  {
    const int li2 = tid + g2.S - (g2.A0 >> 2);
    const vfloat4 y0 = ((const vfloat4*)xl[0])[li2];
    const vfloat4 y1 = ((const vfloat4*)xl[1])[li2];
    const vfloat4 y2 = ((const vfloat4*)xl[2])[li2];
    const vfloat4 de = ((const vfloat4*)dl)[li2];
    const size_t ob = (size_t)g2.b * H_ * FN4 + g2.S + tid;
#pragma unroll 4
    for (int h = 0; h < H_; ++h) {
      const vfloat4 wv = Wp[h];
      vfloat4 o;
      o.x = de.x * fmaf(y2.x, wv.z, fmaf(y1.x, wv.y, fmaf(y0.x, wv.x, wv.w)));
      o.y = de.y * fmaf(y2.y, wv.z, fmaf(y1.y, wv.y, fmaf(y0.y, wv.x, wv.w)));
      o.z = de.z * fmaf(y2.z, wv.z, fmaf(y1.z, wv.y, fmaf(y0.z, wv.x, wv.w)));
      o.w = de.w * fmaf(y2.w, wv.z, fmaf(y1.w, wv.y, fmaf(y0.w, wv.x, wv.w)));
      __builtin_nontemporal_store(o, &og[ob + (size_t)h * FN4]);
    }
  }
}

extern "C" void kernel_launch(void* const* d_in, const int* in_sizes, int n_in,
                              void* d_out, int out_size, void* d_ws, size_t ws_size,
                              hipStream_t stream) {
  const float* x    = (const float*)d_in[0];  // [B,C,F,N]
  const float* mask = (const float*)d_in[1];  // [N,N]
  const float* W    = (const float*)d_in[2];  // [C,H]
  const float* bW   = (const float*)d_in[3];  // [H]
  // d_in[4] = a1 (cancels), d_in[6] = ab (cancels)
  const float* a2   = (const float*)d_in[5];  // [H]
  float* out = (float*)d_out;                 // [B,H,F,N]

  hipLaunchKernelGGL(gat_pipe, dim3(BLOCKS), dim3(THREADS), 0, stream,
                     x, mask, W, bW, a2, out);
}